// Round 13
// baseline (153.687 us; speedup 1.0000x reference)
//
#include <hip/hip_runtime.h>
#include <hip/hip_fp16.h>
#include <math.h>

#define BATCH 16384
#define MAXF 32
#define NFEAT 768
#define FT_OUT 1024
#define CHUNK 32                      // columns per chunk (64-B LDS row)
#define NCHUNK (FT_OUT / CHUNK)       // 32 chunks
#define GROUPS 24                     // stripes per chunk -> 768 blocks = 3/CU
#define CH_HALVES (NFEAT * CHUNK)     // 24576 halves = 48 KiB (STATIC: dynamic LDS
                                      // breaks array reg-promotion, R7/R11)
#define NL2 6                         // features routed via L2 fp32 gather (both slices)

// compile-time component select for unrolled loops (f is a constant after unroll)
#define GET4(a, f) (((f) & 3) == 0 ? (a)[(f) >> 2].x : \
                    ((f) & 3) == 1 ? (a)[(f) >> 2].y : \
                    ((f) & 3) == 2 ? (a)[(f) >> 2].z : (a)[(f) >> 2].w)

typedef unsigned int uint_t;

// Main: R10 structure + feature-split. Features 0..NL2-1 gather fp32 rows from
// L2 (VMEM pipe, fp32 accumulate); features NL2..31 gather f16 rows from LDS
// (DS pipe, hfma2). The two pipes run concurrently at full 3-block/CU occupancy
// (R6 lesson: separate-role hybrid starves the latency-bound L2 path of waves).
// NO __threadfence (R8/R9: device fence = L2 wb-inv = 2.7x slowdown).
__global__ __launch_bounds__(256, 3) void nnboard_main(
    const float* __restrict__ values,
    const int*   __restrict__ stm_idx,
    const int*   __restrict__ nstm_idx,
    const float* __restrict__ ft_w,
    const float* __restrict__ ft_b,
    const float* __restrict__ out_w,
    float*       __restrict__ partials)   // [NCHUNK][BATCH]
{
    __shared__ __half s_tab[CH_HALVES];   // 48 KiB, row stride 32 halves (64 B)

    const int tid = threadIdx.x;
    const int c = blockIdx.x % NCHUNK;    // chunk: cols [32c, 32c+32)
    const int g = blockIdx.x / NCHUNK;    // stripe 0..23
    const __half2 zero2 = __float2half2_rn(0.f);

    // ---- stage chunk c directly from fp32 ft_w: 8 lanes/row, 128-B coalesced
    {
        const int lane8 = tid & 7;
        const int rbase = tid >> 3;
        #pragma unroll
        for (int k = 0; k < NFEAT / 32; ++k) {
            const int r = k * 32 + rbase;
            const float4 f = *(const float4*)(ft_w + (size_t)r * FT_OUT + c * CHUNK + lane8 * 4);
            __half2 h0 = __floats2half2_rn(f.x, f.y);
            __half2 h1 = __floats2half2_rn(f.z, f.w);
            uint2 u;
            u.x = *reinterpret_cast<uint_t*>(&h0);
            u.y = *reinterpret_cast<uint_t*>(&h1);
            *(uint2*)(s_tab + r * CHUNK + lane8 * 4) = u;
        }
    }
    __syncthreads();

    const int grp = tid >> 2;             // 0..63 : sample slot per iteration
    const int j   = tid & 3;              // lane within sample (owns 8 cols)
    const int col0 = c * CHUNK + j * 8;
    const __half* my_tab = s_tab + j * 8; // + row*CHUNK per gathered row

    const float4 bia0 = *(const float4*)(ft_b + col0);
    const float4 bia1 = *(const float4*)(ft_b + col0 + 4);
    const float4 ws0  = *(const float4*)(out_w + col0);
    const float4 ws1  = *(const float4*)(out_w + col0 + 4);
    const float4 wn0  = *(const float4*)(out_w + FT_OUT + col0);
    const float4 wn1  = *(const float4*)(out_w + FT_OUT + col0 + 4);

    for (int it = g; it < BATCH / 64; it += GROUPS) {
        const int b = it * 64 + grp;

        const int4*   sp = (const int4*)(stm_idx + b * MAXF);
        const int4*   np = (const int4*)(nstm_idx + b * MAXF);
        const float4* vp = (const float4*)(values + b * MAXF);
        int4 si[8], ni[8];
        float4 vv[8];
        #pragma unroll
        for (int k = 0; k < 8; ++k) { si[k] = sp[k]; ni[k] = np[k]; vv[k] = vp[k]; }

        // f16 accumulators for the LDS-routed features
        __half2 accs[4] = {zero2, zero2, zero2, zero2};
        __half2 accn[4] = {zero2, zero2, zero2, zero2};
        // fp32 accumulators for the L2-routed features (cols 0-3 / 4-7)
        float4 rsA = make_float4(0.f, 0.f, 0.f, 0.f), rsB = rsA;
        float4 rnA = rsA, rnB = rsA;

        #pragma unroll
        for (int f = 0; f < MAXF; ++f) {
            const int is = GET4(si, f);
            const int in = GET4(ni, f);
            if (f < NL2) {
                // L2 route: 128-B contiguous fp32 per sample (R3-proven shape)
                const float vf = GET4(vv, f);
                const float* ps = ft_w + (size_t)is * FT_OUT + col0;
                const float* pn = ft_w + (size_t)in * FT_OUT + col0;
                const float4 a0 = *(const float4*)(ps);
                const float4 a1 = *(const float4*)(ps + 4);
                const float4 b0 = *(const float4*)(pn);
                const float4 b1 = *(const float4*)(pn + 4);
                rsA.x = fmaf(vf, a0.x, rsA.x); rsA.y = fmaf(vf, a0.y, rsA.y);
                rsA.z = fmaf(vf, a0.z, rsA.z); rsA.w = fmaf(vf, a0.w, rsA.w);
                rsB.x = fmaf(vf, a1.x, rsB.x); rsB.y = fmaf(vf, a1.y, rsB.y);
                rsB.z = fmaf(vf, a1.z, rsB.z); rsB.w = fmaf(vf, a1.w, rsB.w);
                rnA.x = fmaf(vf, b0.x, rnA.x); rnA.y = fmaf(vf, b0.y, rnA.y);
                rnA.z = fmaf(vf, b0.z, rnA.z); rnA.w = fmaf(vf, b0.w, rnA.w);
                rnB.x = fmaf(vf, b1.x, rnB.x); rnB.y = fmaf(vf, b1.y, rnB.y);
                rnB.z = fmaf(vf, b1.z, rnB.z); rnB.w = fmaf(vf, b1.w, rnB.w);
            } else {
                // LDS route (R10-proven)
                const __half2 v2 = __float2half2_rn(GET4(vv, f));
                const uint4 qs = *(const uint4*)(my_tab + is * CHUNK);
                const uint4 qn = *(const uint4*)(my_tab + in * CHUNK);
                accs[0] = __hfma2(*(const __half2*)&qs.x, v2, accs[0]);
                accs[1] = __hfma2(*(const __half2*)&qs.y, v2, accs[1]);
                accs[2] = __hfma2(*(const __half2*)&qs.z, v2, accs[2]);
                accs[3] = __hfma2(*(const __half2*)&qs.w, v2, accs[3]);
                accn[0] = __hfma2(*(const __half2*)&qn.x, v2, accn[0]);
                accn[1] = __hfma2(*(const __half2*)&qn.y, v2, accn[1]);
                accn[2] = __hfma2(*(const __half2*)&qn.z, v2, accn[2]);
                accn[3] = __hfma2(*(const __half2*)&qn.w, v2, accn[3]);
            }
        }

        float p = 0.f;
        {
            const float2 f0 = __half22float2(accs[0]);
            const float2 f1 = __half22float2(accs[1]);
            const float2 f2 = __half22float2(accs[2]);
            const float2 f3 = __half22float2(accs[3]);
            const float2 g0 = __half22float2(accn[0]);
            const float2 g1 = __half22float2(accn[1]);
            const float2 g2 = __half22float2(accn[2]);
            const float2 g3 = __half22float2(accn[3]);
            auto clip = [](float x) { return fminf(fmaxf(x, 0.f), 1.f); };
            p = fmaf(clip(f0.x + rsA.x + bia0.x), ws0.x, p);
            p = fmaf(clip(f0.y + rsA.y + bia0.y), ws0.y, p);
            p = fmaf(clip(f1.x + rsA.z + bia0.z), ws0.z, p);
            p = fmaf(clip(f1.y + rsA.w + bia0.w), ws0.w, p);
            p = fmaf(clip(f2.x + rsB.x + bia1.x), ws1.x, p);
            p = fmaf(clip(f2.y + rsB.y + bia1.y), ws1.y, p);
            p = fmaf(clip(f3.x + rsB.z + bia1.z), ws1.z, p);
            p = fmaf(clip(f3.y + rsB.w + bia1.w), ws1.w, p);
            p = fmaf(clip(g0.x + rnA.x + bia0.x), wn0.x, p);
            p = fmaf(clip(g0.y + rnA.y + bia0.y), wn0.y, p);
            p = fmaf(clip(g1.x + rnA.z + bia0.z), wn0.z, p);
            p = fmaf(clip(g1.y + rnA.w + bia0.w), wn0.w, p);
            p = fmaf(clip(g2.x + rnB.x + bia1.x), wn1.x, p);
            p = fmaf(clip(g2.y + rnB.y + bia1.y), wn1.y, p);
            p = fmaf(clip(g3.x + rnB.z + bia1.z), wn1.z, p);
            p = fmaf(clip(g3.y + rnB.w + bia1.w), wn1.w, p);
        }

        // reduce 4 lanes of the sample group (tid = grp*4 + j, contiguous)
        p += __shfl_down(p, 1, 64);
        p += __shfl_down(p, 2, 64);
        if (j == 0) partials[c * BATCH + b] = p;   // plain store
    }
}

// Epilogue: sum 32 chunk-partials per sample, + out_b, sigmoid.
__global__ __launch_bounds__(256) void reduce_sigmoid_kernel(
    const float* __restrict__ partials,
    const float* __restrict__ out_b,
    float* __restrict__ out)
{
    const int i = blockIdx.x * 256 + threadIdx.x;
    float s = out_b[0];
    #pragma unroll
    for (int k = 0; k < NCHUNK; ++k)
        s += partials[k * BATCH + i];
    out[i] = 1.f / (1.f + expf(-s));
}

extern "C" void kernel_launch(void* const* d_in, const int* in_sizes, int n_in,
                              void* d_out, int out_size, void* d_ws, size_t ws_size,
                              hipStream_t stream) {
    const float* values   = (const float*)d_in[0];
    const int*   stm_idx  = (const int*)d_in[1];
    const int*   nstm_idx = (const int*)d_in[2];
    const float* ft_w     = (const float*)d_in[3];
    const float* ft_b     = (const float*)d_in[4];
    const float* out_w    = (const float*)d_in[5];
    const float* out_b    = (const float*)d_in[6];
    float*       out      = (float*)d_out;

    float* partials = (float*)d_ws;   // [32][16384] f32 = 2 MB, fully overwritten

    nnboard_main<<<NCHUNK * GROUPS, 256, 0, stream>>>(
        values, stm_idx, nstm_idx, ft_w, ft_b, out_w, partials);
    reduce_sigmoid_kernel<<<BATCH / 256, 256, 0, stream>>>(partials, out_b, out);
}

// Round 14
// 110.247 us; speedup vs baseline: 1.3940x; 1.3940x over previous
//
#include <hip/hip_runtime.h>
#include <hip/hip_fp16.h>
#include <math.h>

#define BATCH 16384
#define MAXF 32
#define NFEAT 768
#define FT_OUT 1024
#define CHUNK 32                      // columns per chunk (64-B LDS row)
#define NCHUNK (FT_OUT / CHUNK)       // 32 chunks
#define GROUPS 24                     // stripes per chunk -> 768 blocks = 3/CU
#define CH_HALVES (NFEAT * CHUNK)     // 24576 halves = 48 KiB

// compile-time component select for unrolled loops (f is a constant after unroll)
#define GET4(a, f) (((f) & 3) == 0 ? (a)[(f) >> 2].x : \
                    ((f) & 3) == 1 ? (a)[(f) >> 2].y : \
                    ((f) & 3) == 2 ? (a)[(f) >> 2].z : (a)[(f) >> 2].w)

typedef unsigned int uint_t;

// Main: stage fp32 chunk -> f16 LDS, stream samples, write per-chunk partial
// logits with PLAIN STORES (each (chunk,sample) pair written exactly once ->
// no zero-init, no atomics, no memset dispatch).
// Hard-won invariants (R1-R13):
//  - static __shared__ only: dynamic LDS breaks array reg-promotion (VGPR
//    80 -> 32, scratch spills, 2.5x slower; R7/R11).
//  - NO __threadfence: device fence = per-block L2 writeback-invalidate,
//    evicts the L2-resident table mid-run (R8 136us vs R9 49us, identical ISA).
//  - 48 KiB / 3 blocks/CU is the occupancy sweet spot; 60/96 KiB variants
//    are latency-exposed (R5/R7/R11/R12).
//  - 64-B rows' parity bank conflicts (+50% on b128) are structural; both
//    padding (R5) and 128-B rows (R12) lose more elsewhere.
//  - no L2-side gather assist: 16-line/instr request shapes are rate-bound
//    and thrash L2 (R6, R13).
__global__ __launch_bounds__(256, 3) void nnboard_main(
    const float* __restrict__ values,
    const int*   __restrict__ stm_idx,
    const int*   __restrict__ nstm_idx,
    const float* __restrict__ ft_w,
    const float* __restrict__ ft_b,
    const float* __restrict__ out_w,
    float*       __restrict__ partials)   // [NCHUNK][BATCH]
{
    __shared__ __half s_tab[CH_HALVES];   // 48 KiB, row stride 32 halves (64 B)

    const int tid = threadIdx.x;
    const int c = blockIdx.x % NCHUNK;    // chunk: cols [32c, 32c+32)
    const int g = blockIdx.x / NCHUNK;    // stripe 0..23
    const __half2 zero2 = __float2half2_rn(0.f);

    // ---- stage chunk c directly from fp32 ft_w: 8 lanes/row, 128-B coalesced
    {
        const int lane8 = tid & 7;
        const int rbase = tid >> 3;
        #pragma unroll
        for (int k = 0; k < NFEAT / 32; ++k) {
            const int r = k * 32 + rbase;
            const float4 f = *(const float4*)(ft_w + (size_t)r * FT_OUT + c * CHUNK + lane8 * 4);
            __half2 h0 = __floats2half2_rn(f.x, f.y);
            __half2 h1 = __floats2half2_rn(f.z, f.w);
            uint2 u;
            u.x = *reinterpret_cast<uint_t*>(&h0);
            u.y = *reinterpret_cast<uint_t*>(&h1);
            *(uint2*)(s_tab + r * CHUNK + lane8 * 4) = u;
        }
    }
    __syncthreads();

    const int grp = tid >> 2;             // 0..63 : sample slot per iteration
    const int j   = tid & 3;              // lane within sample (owns 8 cols)
    const int col0 = c * CHUNK + j * 8;
    const __half* my_tab = s_tab + j * 8; // + row*CHUNK per gathered row

    const float4 bia0 = *(const float4*)(ft_b + col0);
    const float4 bia1 = *(const float4*)(ft_b + col0 + 4);
    const float4 ws0  = *(const float4*)(out_w + col0);
    const float4 ws1  = *(const float4*)(out_w + col0 + 4);
    const float4 wn0  = *(const float4*)(out_w + FT_OUT + col0);
    const float4 wn1  = *(const float4*)(out_w + FT_OUT + col0 + 4);

    for (int it = g; it < BATCH / 64; it += GROUPS) {
        const int b = it * 64 + grp;

        const int4*   sp = (const int4*)(stm_idx + b * MAXF);
        const int4*   np = (const int4*)(nstm_idx + b * MAXF);
        const float4* vp = (const float4*)(values + b * MAXF);
        int4 si[8], ni[8];
        float4 vv[8];
        #pragma unroll
        for (int k = 0; k < 8; ++k) { si[k] = sp[k]; ni[k] = np[k]; vv[k] = vp[k]; }

        __half2 accs[4] = {zero2, zero2, zero2, zero2};
        __half2 accn[4] = {zero2, zero2, zero2, zero2};

        #pragma unroll
        for (int f = 0; f < MAXF; ++f) {
            const int is = GET4(si, f);
            const int in = GET4(ni, f);
            const __half2 v2 = __float2half2_rn(GET4(vv, f));
            const uint4 qs = *(const uint4*)(my_tab + is * CHUNK);
            const uint4 qn = *(const uint4*)(my_tab + in * CHUNK);
            accs[0] = __hfma2(*(const __half2*)&qs.x, v2, accs[0]);
            accs[1] = __hfma2(*(const __half2*)&qs.y, v2, accs[1]);
            accs[2] = __hfma2(*(const __half2*)&qs.z, v2, accs[2]);
            accs[3] = __hfma2(*(const __half2*)&qs.w, v2, accs[3]);
            accn[0] = __hfma2(*(const __half2*)&qn.x, v2, accn[0]);
            accn[1] = __hfma2(*(const __half2*)&qn.y, v2, accn[1]);
            accn[2] = __hfma2(*(const __half2*)&qn.z, v2, accn[2]);
            accn[3] = __hfma2(*(const __half2*)&qn.w, v2, accn[3]);
        }

        float p = 0.f;
        {
            const float2 f0 = __half22float2(accs[0]);
            const float2 f1 = __half22float2(accs[1]);
            const float2 f2 = __half22float2(accs[2]);
            const float2 f3 = __half22float2(accs[3]);
            const float2 g0 = __half22float2(accn[0]);
            const float2 g1 = __half22float2(accn[1]);
            const float2 g2 = __half22float2(accn[2]);
            const float2 g3 = __half22float2(accn[3]);
            auto clip = [](float x) { return fminf(fmaxf(x, 0.f), 1.f); };
            p = fmaf(clip(f0.x + bia0.x), ws0.x, p);
            p = fmaf(clip(f0.y + bia0.y), ws0.y, p);
            p = fmaf(clip(f1.x + bia0.z), ws0.z, p);
            p = fmaf(clip(f1.y + bia0.w), ws0.w, p);
            p = fmaf(clip(f2.x + bia1.x), ws1.x, p);
            p = fmaf(clip(f2.y + bia1.y), ws1.y, p);
            p = fmaf(clip(f3.x + bia1.z), ws1.z, p);
            p = fmaf(clip(f3.y + bia1.w), ws1.w, p);
            p = fmaf(clip(g0.x + bia0.x), wn0.x, p);
            p = fmaf(clip(g0.y + bia0.y), wn0.y, p);
            p = fmaf(clip(g1.x + bia0.z), wn0.z, p);
            p = fmaf(clip(g1.y + bia0.w), wn0.w, p);
            p = fmaf(clip(g2.x + bia1.x), wn1.x, p);
            p = fmaf(clip(g2.y + bia1.y), wn1.y, p);
            p = fmaf(clip(g3.x + bia1.z), wn1.z, p);
            p = fmaf(clip(g3.y + bia1.w), wn1.w, p);
        }

        // reduce 4 lanes of the sample group (tid = grp*4 + j, contiguous)
        p += __shfl_down(p, 1, 64);
        p += __shfl_down(p, 2, 64);
        if (j == 0) partials[c * BATCH + b] = p;   // plain store, 16 lanes/wave
    }
}

// Epilogue: sum 32 chunk-partials per sample (coalesced: stride-BATCH rows,
// consecutive samples -> consecutive addresses), + out_b, sigmoid.
__global__ __launch_bounds__(256) void reduce_sigmoid_kernel(
    const float* __restrict__ partials,
    const float* __restrict__ out_b,
    float* __restrict__ out)
{
    const int i = blockIdx.x * 256 + threadIdx.x;
    float s = out_b[0];
    #pragma unroll
    for (int k = 0; k < NCHUNK; ++k)
        s += partials[k * BATCH + i];
    out[i] = 1.f / (1.f + expf(-s));
}

extern "C" void kernel_launch(void* const* d_in, const int* in_sizes, int n_in,
                              void* d_out, int out_size, void* d_ws, size_t ws_size,
                              hipStream_t stream) {
    const float* values   = (const float*)d_in[0];
    const int*   stm_idx  = (const int*)d_in[1];
    const int*   nstm_idx = (const int*)d_in[2];
    const float* ft_w     = (const float*)d_in[3];
    const float* ft_b     = (const float*)d_in[4];
    const float* out_w    = (const float*)d_in[5];
    const float* out_b    = (const float*)d_in[6];
    float*       out      = (float*)d_out;

    float* partials = (float*)d_ws;   // [32][16384] f32 = 2 MB, fully overwritten

    nnboard_main<<<NCHUNK * GROUPS, 256, 0, stream>>>(
        values, stm_idx, nstm_idx, ft_w, ft_b, out_w, partials);
    reduce_sigmoid_kernel<<<BATCH / 256, 256, 0, stream>>>(partials, out_b, out);
}